// Round 8
// baseline (351.678 us; speedup 1.0000x reference)
//
#include <hip/hip_runtime.h>

constexpr int NN = 50000;   // nodes
constexpr int NE = 800000;  // edges
constexpr int NG = 64;      // graphs
constexpr int DI = 64;      // in dim
constexpr int DH = 128;     // hidden dim
constexpr int DO = 3;       // out dim

constexpr int TOT = 2 * NN;  // combined [src-counts | dst-counts]
constexpr int SCAN_B = 256;
constexpr int NB_SCAN = (TOT + SCAN_B - 1) / SCAN_B;  // 391

// ---------------- CSR build (src-sorted adjacency via 2-stage counting sort) ----------------
__global__ void k_zero(int* cnt) {
    int i = blockIdx.x * blockDim.x + threadIdx.x;
    if (i < TOT) cnt[i] = 0;
}

// combined histogram: cnt[s] = out-degree, cnt[NN+d] = in-degree
__global__ void k_hist2(const int* __restrict__ src, const int* __restrict__ dst,
                        int* __restrict__ cnt) {
    int e = blockIdx.x * blockDim.x + threadIdx.x;
    if (e < NE) {
        atomicAdd(&cnt[src[e]], 1);
        atomicAdd(&cnt[NN + dst[e]], 1);
    }
}

__global__ void k_scan1(const int* __restrict__ cnt, int* __restrict__ pos,
                        int* __restrict__ partial) {
    __shared__ int sm[SCAN_B];
    int i = blockIdx.x * SCAN_B + threadIdx.x;
    int v = (i < TOT) ? cnt[i] : 0;
    sm[threadIdx.x] = v;
    __syncthreads();
    for (int off = 1; off < SCAN_B; off <<= 1) {
        int add = (threadIdx.x >= off) ? sm[threadIdx.x - off] : 0;
        __syncthreads();
        sm[threadIdx.x] += add;
        __syncthreads();
    }
    if (i < TOT) pos[i] = sm[threadIdx.x] - v;  // block-local exclusive
    if (threadIdx.x == SCAN_B - 1) partial[blockIdx.x] = sm[SCAN_B - 1];
}

__global__ void k_scan2(int* partial) {  // single block of 512, NB_SCAN=391 <= 512
    __shared__ int sm[512];
    int v = (threadIdx.x < NB_SCAN) ? partial[threadIdx.x] : 0;
    sm[threadIdx.x] = v;
    __syncthreads();
    for (int off = 1; off < 512; off <<= 1) {
        int add = (threadIdx.x >= off) ? sm[threadIdx.x - off] : 0;
        __syncthreads();
        sm[threadIdx.x] += add;
        __syncthreads();
    }
    if (threadIdx.x < NB_SCAN) partial[threadIdx.x] = sm[threadIdx.x] - v;  // exclusive
}

// finalize positions: pos[0..NN)=srcptr, pos[NN..2NN)=dst rowptr (NE-adjusted);
// copies into cursor; computes dinv from in-degree (cnt intact here).
__global__ void k_scan3b(int* __restrict__ pos, const int* __restrict__ partial,
                         const int* __restrict__ cnt, int* __restrict__ cursor,
                         float* __restrict__ dinv) {
    int i = blockIdx.x * blockDim.x + threadIdx.x;
    if (i < TOT) {
        int P = pos[i] + partial[i >> 8];
        if (i >= NN) {
            P -= NE;  // dst-side positions are offset by total src count (=NE)
            dinv[i - NN] = rsqrtf((float)(cnt[i] + 1));  // +1 self-loop
        }
        pos[i] = P;
        cursor[i] = P;
    } else if (i == TOT) {
        pos[TOT] = NE;  // rowptr sentinel (pos+NN)[NN]
    }
}

// stage 1: CSC fill (src-major order, arbitrary within-src order)
__global__ void k_fillcsc(const int* __restrict__ src, const int* __restrict__ dst,
                          int* __restrict__ cursor, int2* __restrict__ csc) {
    int e = blockIdx.x * blockDim.x + threadIdx.x;
    if (e < NE) {
        int s = src[e], d = dst[e];
        int slot = atomicAdd(&cursor[s], 1);
        csc[slot] = make_int2(d, s);
    }
}

// stage 2: walk CSC in src-sorted order, scatter to dst rows -> rows ~sorted by src
__global__ void k_stage2(const int2* __restrict__ csc, int* __restrict__ cursor,
                         const float* __restrict__ dinv, int2* __restrict__ csr) {
    int i = blockIdx.x * blockDim.x + threadIdx.x;
    if (i < NE) {
        int2 c = csc[i];
        int d = c.x, s = c.y;
        float w = dinv[s] * dinv[d];
        int slot = atomicAdd(&cursor[NN + d], 1);
        csr[slot] = make_int2(s, __float_as_int(w));
    }
}

// ---------------- gather aggregation (src-sorted rows -> L2-resident sweep) ----------------
// out[n] = dinv[n]^2*h[n] + sum_in w_e * h[src_e]   (+bias, relu)
template <int D, bool BIAS_RELU>
__global__ __launch_bounds__(256) void k_agg3(const float* __restrict__ h,
                                              const int2* __restrict__ csr,
                                              const int* __restrict__ rowptr,
                                              const float* __restrict__ dinv,
                                              const float* __restrict__ bias,
                                              float* __restrict__ out) {
    constexpr int SUB = D / 4;        // lanes per node (16 for D=64, 32 for D=128)
    constexpr int NPB = 256 / SUB;    // nodes per block
    const int sub = threadIdx.x / SUB;
    const int sl = threadIdx.x % SUB;
    const int node = blockIdx.x * NPB + sub;
    if (node >= NN) return;

    const float dn = dinv[node];
    float4 acc;
    {
        float4 hv = *reinterpret_cast<const float4*>(h + (size_t)node * D + sl * 4);
        float w = dn * dn;
        acc.x = w * hv.x; acc.y = w * hv.y; acc.z = w * hv.z; acc.w = w * hv.w;
    }
    int j = rowptr[node];
    const int end = rowptr[node + 1];
    if ((j & 1) && j < end) {
        int2 e0 = csr[j];
        float w0 = __int_as_float(e0.y);
        float4 g0 = *reinterpret_cast<const float4*>(h + (size_t)e0.x * D + sl * 4);
        acc.x = fmaf(w0, g0.x, acc.x); acc.y = fmaf(w0, g0.y, acc.y);
        acc.z = fmaf(w0, g0.z, acc.z); acc.w = fmaf(w0, g0.w, acc.w);
        ++j;
    }
    for (; j + 4 <= end; j += 4) {
        int4 p0 = *reinterpret_cast<const int4*>(&csr[j]);
        int4 p1 = *reinterpret_cast<const int4*>(&csr[j + 2]);
        float4 g0 = *reinterpret_cast<const float4*>(h + (size_t)p0.x * D + sl * 4);
        float4 g1 = *reinterpret_cast<const float4*>(h + (size_t)p0.z * D + sl * 4);
        float4 g2 = *reinterpret_cast<const float4*>(h + (size_t)p1.x * D + sl * 4);
        float4 g3 = *reinterpret_cast<const float4*>(h + (size_t)p1.z * D + sl * 4);
        float w0 = __int_as_float(p0.y), w1 = __int_as_float(p0.w);
        float w2 = __int_as_float(p1.y), w3 = __int_as_float(p1.w);
        acc.x = fmaf(w0, g0.x, acc.x); acc.y = fmaf(w0, g0.y, acc.y);
        acc.z = fmaf(w0, g0.z, acc.z); acc.w = fmaf(w0, g0.w, acc.w);
        acc.x = fmaf(w1, g1.x, acc.x); acc.y = fmaf(w1, g1.y, acc.y);
        acc.z = fmaf(w1, g1.z, acc.z); acc.w = fmaf(w1, g1.w, acc.w);
        acc.x = fmaf(w2, g2.x, acc.x); acc.y = fmaf(w2, g2.y, acc.y);
        acc.z = fmaf(w2, g2.z, acc.z); acc.w = fmaf(w2, g2.w, acc.w);
        acc.x = fmaf(w3, g3.x, acc.x); acc.y = fmaf(w3, g3.y, acc.y);
        acc.z = fmaf(w3, g3.z, acc.z); acc.w = fmaf(w3, g3.w, acc.w);
    }
    if (j + 2 <= end) {
        int4 p0 = *reinterpret_cast<const int4*>(&csr[j]);
        float4 g0 = *reinterpret_cast<const float4*>(h + (size_t)p0.x * D + sl * 4);
        float4 g1 = *reinterpret_cast<const float4*>(h + (size_t)p0.z * D + sl * 4);
        float w0 = __int_as_float(p0.y), w1 = __int_as_float(p0.w);
        acc.x = fmaf(w0, g0.x, acc.x); acc.y = fmaf(w0, g0.y, acc.y);
        acc.z = fmaf(w0, g0.z, acc.z); acc.w = fmaf(w0, g0.w, acc.w);
        acc.x = fmaf(w1, g1.x, acc.x); acc.y = fmaf(w1, g1.y, acc.y);
        acc.z = fmaf(w1, g1.z, acc.z); acc.w = fmaf(w1, g1.w, acc.w);
        j += 2;
    }
    if (j < end) {
        int2 e0 = csr[j];
        float w0 = __int_as_float(e0.y);
        float4 g0 = *reinterpret_cast<const float4*>(h + (size_t)e0.x * D + sl * 4);
        acc.x = fmaf(w0, g0.x, acc.x); acc.y = fmaf(w0, g0.y, acc.y);
        acc.z = fmaf(w0, g0.z, acc.z); acc.w = fmaf(w0, g0.w, acc.w);
    }
    if (BIAS_RELU) {
        float4 bb = *reinterpret_cast<const float4*>(bias + sl * 4);
        acc.x = fmaxf(acc.x + bb.x, 0.0f);
        acc.y = fmaxf(acc.y + bb.y, 0.0f);
        acc.z = fmaxf(acc.z + bb.z, 0.0f);
        acc.w = fmaxf(acc.w + bb.w, 0.0f);
    }
    *reinterpret_cast<float4*>(out + (size_t)node * D + sl * 4) = acc;
}

// ---------------- GEMM v3 (unchanged — out of top-5) ----------------
__device__ inline float4 fmaf4(float s, float4 w, float4 a) {
    a.x = fmaf(s, w.x, a.x); a.y = fmaf(s, w.y, a.y);
    a.z = fmaf(s, w.z, a.z); a.w = fmaf(s, w.w, a.w);
    return a;
}

template <int DIN, bool BIAS_RELU>
__global__ __launch_bounds__(256) void k_gemm3(const float* __restrict__ A,
                                               const float* __restrict__ W,
                                               const float* __restrict__ bias,
                                               float* __restrict__ C) {
    constexpr int KT = 32;
    constexpr int NT = DIN / KT;
    constexpr int AP = KT + 4;
    __shared__ float sW[KT * DH];
    __shared__ float sA[64 * AP];
    const int t = threadIdx.x;
    const int cg = t & 31;
    const int rg = t >> 5;
    const int row0 = blockIdx.x * 64;
    const int sr = t >> 2;
    const int kq = t & 3;

    float4 acc[8];
#pragma unroll
    for (int j = 0; j < 8; ++j) acc[j] = make_float4(0.f, 0.f, 0.f, 0.f);

    for (int tile = 0; tile < NT; ++tile) {
        if (tile) __syncthreads();
        {
            const float4* Wg = reinterpret_cast<const float4*>(W + tile * KT * DH);
            float4* sW4 = reinterpret_cast<float4*>(sW);
#pragma unroll
            for (int i = 0; i < (KT * DH / 4) / 256; ++i)
                sW4[t + 256 * i] = Wg[t + 256 * i];
        }
        {
            int gr = row0 + sr;
            float4 v0 = make_float4(0.f, 0.f, 0.f, 0.f), v1 = v0;
            if (gr < NN) {
                const float* Ag = A + (size_t)gr * DIN + tile * KT + kq * 8;
                v0 = *reinterpret_cast<const float4*>(Ag);
                v1 = *reinterpret_cast<const float4*>(Ag + 4);
            }
            *reinterpret_cast<float4*>(&sA[sr * AP + kq * 8]) = v0;
            *reinterpret_cast<float4*>(&sA[sr * AP + kq * 8 + 4]) = v1;
        }
        __syncthreads();
#pragma unroll 2
        for (int kk = 0; kk < KT; kk += 4) {
            float4 w0 = *reinterpret_cast<const float4*>(&sW[(kk + 0) * DH + cg * 4]);
            float4 w1 = *reinterpret_cast<const float4*>(&sW[(kk + 1) * DH + cg * 4]);
            float4 w2 = *reinterpret_cast<const float4*>(&sW[(kk + 2) * DH + cg * 4]);
            float4 w3 = *reinterpret_cast<const float4*>(&sW[(kk + 3) * DH + cg * 4]);
#pragma unroll
            for (int j = 0; j < 8; ++j) {
                float4 a = *reinterpret_cast<const float4*>(&sA[(rg * 8 + j) * AP + kk]);
                acc[j] = fmaf4(a.x, w0, acc[j]);
                acc[j] = fmaf4(a.y, w1, acc[j]);
                acc[j] = fmaf4(a.z, w2, acc[j]);
                acc[j] = fmaf4(a.w, w3, acc[j]);
            }
        }
    }
    float4 bb = make_float4(0.f, 0.f, 0.f, 0.f);
    if (BIAS_RELU) bb = *reinterpret_cast<const float4*>(bias + cg * 4);
#pragma unroll
    for (int j = 0; j < 8; ++j) {
        int gr = row0 + rg * 8 + j;
        if (gr < NN) {
            float4 r = acc[j];
            if (BIAS_RELU) {
                r.x = fmaxf(r.x + bb.x, 0.f); r.y = fmaxf(r.y + bb.y, 0.f);
                r.z = fmaxf(r.z + bb.z, 0.f); r.w = fmaxf(r.w + bb.w, 0.f);
            }
            *reinterpret_cast<float4*>(C + (size_t)gr * DH + cg * 4) = r;
        }
    }
}

// ---------------- pooling ----------------
__global__ void k_gstart_zero(const int* __restrict__ batch, int* __restrict__ gstart,
                              float* __restrict__ pooled) {
    int i = blockIdx.x * blockDim.x + threadIdx.x;
    if (i < NG * DH) pooled[i] = 0.0f;
    if (blockIdx.x == 0 && threadIdx.x <= NG) {
        int g = threadIdx.x;
        int lo = 0, hi = NN;
        while (lo < hi) {
            int mid = (lo + hi) >> 1;
            if (batch[mid] < g) lo = mid + 1; else hi = mid;
        }
        gstart[g] = lo;
    }
}

constexpr int POOL_CHUNK = 64;
__global__ __launch_bounds__(256) void k_pool2(const float* __restrict__ h,
                                               const int* __restrict__ batch,
                                               float* __restrict__ pooled) {
    const int c = threadIdx.x & 127;
    const int half = threadIdx.x >> 7;
    const int n0 = blockIdx.x * POOL_CHUNK;
    const int nEnd = min(n0 + POOL_CHUNK, NN);
    float acc = 0.0f;
    int gcur = -1;
    for (int n = n0 + half; n < nEnd; n += 2) {
        int g = batch[n];
        if (g != gcur) {
            if (gcur >= 0) atomicAdd(&pooled[gcur * DH + c], acc);
            acc = 0.0f;
            gcur = g;
        }
        acc += h[(size_t)n * DH + c];
    }
    if (gcur >= 0) atomicAdd(&pooled[gcur * DH + c], acc);
}

__global__ void k_head(const float* __restrict__ pooled, const int* __restrict__ gstart,
                       const float* __restrict__ Wf, const float* __restrict__ bf,
                       float* __restrict__ out) {
    int t = threadIdx.x;
    if (t >= NG * DO) return;
    int g = t / DO, o = t - g * DO;
    float acc = 0.0f;
    for (int k = 0; k < DH; ++k) acc += pooled[g * DH + k] * Wf[k * DO + o];
    float cnt = fmaxf((float)(gstart[g + 1] - gstart[g]), 1.0f);
    out[t] = acc / cnt + bf[o];
}

extern "C" void kernel_launch(void* const* d_in, const int* in_sizes, int n_in,
                              void* d_out, int out_size, void* d_ws, size_t ws_size,
                              hipStream_t stream) {
    const float* x   = (const float*)d_in[0];
    const int* ei    = (const int*)d_in[1];  // [2, NE] row-major
    const int* batch = (const int*)d_in[2];
    const float* W1  = (const float*)d_in[3];
    const float* b1  = (const float*)d_in[4];
    const float* W2  = (const float*)d_in[5];
    const float* b2  = (const float*)d_in[6];
    const float* Wf  = (const float*)d_in[7];
    const float* bf  = (const float*)d_in[8];
    float* out = (float*)d_out;

    const int* src = ei;
    const int* dst = ei + NE;

    // workspace layout (~58.24 MB total, same budget as previous rounds)
    int* pos      = (int*)d_ws;              // TOT+1 used, pad 100008
    int* partial  = pos + 100008;            // 512
    int* gstart   = partial + 512;           // 72, pad 80
    int2* csr     = (int2*)(gstart + 80);    // NE int2; byte off 402400 (16B-aligned)
    float* dinv   = (float*)(csr + NE);      // 50048
    float* buf1   = dinv + 50048;            // 6.4M floats
    float* buf2   = buf1 + 6400000;          // 6.4M floats
    float* pooled = buf2 + 6400000;          // 8192
    // transient aliases (dead before their hosts are first written):
    int2* csc     = (int2*)buf1;             // NE int2, dead after k_stage2 (< agg1 write)
    int* cnt      = (int*)buf2;              // TOT, dead after k_scan3b (< gemm1 write)
    int* cursor   = cnt + TOT;               // TOT, dead after k_stage2 (< gemm1 write)

    const int B = 256;
    k_zero<<<(TOT + B - 1) / B, B, 0, stream>>>(cnt);
    k_hist2<<<(NE + B - 1) / B, B, 0, stream>>>(src, dst, cnt);
    k_scan1<<<NB_SCAN, SCAN_B, 0, stream>>>(cnt, pos, partial);
    k_scan2<<<1, 512, 0, stream>>>(partial);
    k_scan3b<<<(TOT + B) / B + 1, B, 0, stream>>>(pos, partial, cnt, cursor, dinv);
    k_fillcsc<<<(NE + B - 1) / B, B, 0, stream>>>(src, dst, cursor, csc);
    k_stage2<<<(NE + B - 1) / B, B, 0, stream>>>(csc, cursor, dinv, csr);

    const int* rowptr = pos + NN;  // dst row pointers (NE-adjusted), sentinel at [NN]
    const int gemmGrid = (NN + 63) / 64;  // 782

    // layer 1: agg first (D=64, linearity), then GEMM + bias + relu
    k_agg3<DI, false><<<NN / 16, 256, 0, stream>>>(x, csr, rowptr, dinv, nullptr, buf1);
    k_gemm3<DI, true><<<gemmGrid, 256, 0, stream>>>(buf1, W1, b1, buf2);  // h1

    // layer 2: GEMM first, then agg + bias + relu
    k_gemm3<DH, false><<<gemmGrid, 256, 0, stream>>>(buf2, W2, nullptr, buf1);  // t = h1@W2
    k_agg3<DH, true><<<NN / 8, 256, 0, stream>>>(buf1, csr, rowptr, dinv, b2, buf2);  // h2

    // pool + head
    k_gstart_zero<<<32, 256, 0, stream>>>(batch, gstart, pooled);
    k_pool2<<<(NN + POOL_CHUNK - 1) / POOL_CHUNK, 256, 0, stream>>>(buf2, batch, pooled);
    k_head<<<1, 256, 0, stream>>>(pooled, gstart, Wf, bf, out);
}

// Round 9
// 232.015 us; speedup vs baseline: 1.5158x; 1.5158x over previous
//
#include <hip/hip_runtime.h>

constexpr int NN = 50000;   // nodes
constexpr int NE = 800000;  // edges
constexpr int NG = 64;      // graphs
constexpr int DI = 64;      // in dim
constexpr int DH = 128;     // hidden dim
constexpr int DO = 3;       // out dim

constexpr int SCAN_B = 256;
constexpr int NB_SCAN = (NN + SCAN_B - 1) / SCAN_B;  // 196

typedef unsigned int u32;

// ---------------- bf16 helpers ----------------
__device__ inline float blo(u32 u) { return __uint_as_float(u << 16); }
__device__ inline float bhi(u32 u) { return __uint_as_float(u & 0xffff0000u); }
__device__ inline u32 f2b(float f) {  // RNE round to bf16 (returns 16-bit pattern)
    u32 u = __float_as_uint(f);
    return (u + 0x7fffu + ((u >> 16) & 1u)) >> 16;
}
__device__ inline void fma8(float w, uint4 v, float acc[8]) {
    acc[0] = fmaf(w, blo(v.x), acc[0]); acc[1] = fmaf(w, bhi(v.x), acc[1]);
    acc[2] = fmaf(w, blo(v.y), acc[2]); acc[3] = fmaf(w, bhi(v.y), acc[3]);
    acc[4] = fmaf(w, blo(v.z), acc[4]); acc[5] = fmaf(w, bhi(v.z), acc[5]);
    acc[6] = fmaf(w, blo(v.w), acc[6]); acc[7] = fmaf(w, bhi(v.w), acc[7]);
}

// ---------------- x -> bf16 ----------------
__global__ void k_tobf16(const float* __restrict__ x, uint4* __restrict__ xb) {
    int i = blockIdx.x * blockDim.x + threadIdx.x;  // over NN*DI/8
    if (i >= NN * DI / 8) return;
    float4 a = reinterpret_cast<const float4*>(x)[i * 2];
    float4 b = reinterpret_cast<const float4*>(x)[i * 2 + 1];
    uint4 o;
    o.x = f2b(a.x) | (f2b(a.y) << 16);
    o.y = f2b(a.z) | (f2b(a.w) << 16);
    o.z = f2b(b.x) | (f2b(b.y) << 16);
    o.w = f2b(b.z) | (f2b(b.w) << 16);
    xb[i] = o;
}

// ---------------- CSR build (round-7 single-stage version) ----------------
__global__ void k_zero_cnt(int* cnt) {
    int i = blockIdx.x * blockDim.x + threadIdx.x;
    if (i < NN) cnt[i] = 0;
}

__global__ void k_hist(const int* __restrict__ dst, int* __restrict__ cnt) {
    int e = blockIdx.x * blockDim.x + threadIdx.x;
    if (e < NE) atomicAdd(&cnt[dst[e]], 1);
}

__global__ void k_scan1(const int* __restrict__ cnt, int* __restrict__ rowptr,
                        int* __restrict__ partial) {
    __shared__ int sm[SCAN_B];
    int i = blockIdx.x * SCAN_B + threadIdx.x;
    int v = (i < NN) ? cnt[i] : 0;
    sm[threadIdx.x] = v;
    __syncthreads();
    for (int off = 1; off < SCAN_B; off <<= 1) {
        int add = (threadIdx.x >= off) ? sm[threadIdx.x - off] : 0;
        __syncthreads();
        sm[threadIdx.x] += add;
        __syncthreads();
    }
    if (i < NN) rowptr[i] = sm[threadIdx.x] - v;  // block-local exclusive
    if (threadIdx.x == SCAN_B - 1) partial[blockIdx.x] = sm[SCAN_B - 1];
}

__global__ void k_scan2(int* partial) {  // single block, NB_SCAN <= 256
    __shared__ int sm[SCAN_B];
    int v = (threadIdx.x < NB_SCAN) ? partial[threadIdx.x] : 0;
    sm[threadIdx.x] = v;
    __syncthreads();
    for (int off = 1; off < SCAN_B; off <<= 1) {
        int add = (threadIdx.x >= off) ? sm[threadIdx.x - off] : 0;
        __syncthreads();
        sm[threadIdx.x] += add;
        __syncthreads();
    }
    if (threadIdx.x < NB_SCAN) partial[threadIdx.x] = sm[threadIdx.x] - v;  // exclusive
}

// finalizes rowptr, computes dinv from cnt, then re-inits cnt as the fill cursor
__global__ void k_scan3(int* __restrict__ rowptr, const int* __restrict__ partial,
                        int* __restrict__ cnt_cursor, float* __restrict__ dinv) {
    int i = blockIdx.x * blockDim.x + threadIdx.x;
    if (i < NN) {
        int r = rowptr[i] + partial[i >> 8];
        rowptr[i] = r;
        dinv[i] = rsqrtf((float)(cnt_cursor[i] + 1));  // read cnt BEFORE overwrite
        cnt_cursor[i] = r;
    }
    if (i == NN) rowptr[NN] = NE;
}

// fill packed (src, w) per edge; w = dinv[s]*dinv[d] reused by both layers
__global__ void k_fill(const int* __restrict__ src, const int* __restrict__ dst,
                       int* __restrict__ cursor, const float* __restrict__ dinv,
                       int2* __restrict__ csr) {
    int e = blockIdx.x * blockDim.x + threadIdx.x;
    if (e < NE) {
        int s = src[e], d = dst[e];
        int slot = atomicAdd(&cursor[d], 1);
        float w = dinv[s] * dinv[d];
        csr[slot] = make_int2(s, __float_as_int(w));
    }
}

// ---------------- gather aggregation over a bf16 table ----------------
// out[n] = dinv[n]^2*hb[n] + sum_in w_e * hb[src_e]   (+bias, relu)
// 8 channels (16 B) per lane; D/8 lanes per node.
template <int D, bool BIAS_RELU, bool BF16OUT>
__global__ __launch_bounds__(256) void k_aggb(const ushort* __restrict__ hb,
                                              const int2* __restrict__ csr,
                                              const int* __restrict__ rowptr,
                                              const float* __restrict__ dinv,
                                              const float* __restrict__ bias,
                                              void* __restrict__ out) {
    constexpr int SUB = D / 8;        // lanes per node (8 for D=64, 16 for D=128)
    constexpr int NPB = 256 / SUB;    // nodes per block
    const int sub = threadIdx.x / SUB;
    const int sl = threadIdx.x % SUB;
    const int node = blockIdx.x * NPB + sub;
    if (node >= NN) return;

    const float dn = dinv[node];
    float acc[8];
    {
        uint4 v = *reinterpret_cast<const uint4*>(hb + (size_t)node * D + sl * 8);
        float w = dn * dn;
        acc[0] = w * blo(v.x); acc[1] = w * bhi(v.x);
        acc[2] = w * blo(v.y); acc[3] = w * bhi(v.y);
        acc[4] = w * blo(v.z); acc[5] = w * bhi(v.z);
        acc[6] = w * blo(v.w); acc[7] = w * bhi(v.w);
    }
    int j = rowptr[node];
    const int end = rowptr[node + 1];
    if ((j & 1) && j < end) {  // align to even for int4 pair loads
        int2 e0 = csr[j];
        uint4 g0 = *reinterpret_cast<const uint4*>(hb + (size_t)e0.x * D + sl * 8);
        fma8(__int_as_float(e0.y), g0, acc);
        ++j;
    }
    for (; j + 4 <= end; j += 4) {
        int4 p0 = *reinterpret_cast<const int4*>(&csr[j]);
        int4 p1 = *reinterpret_cast<const int4*>(&csr[j + 2]);
        uint4 g0 = *reinterpret_cast<const uint4*>(hb + (size_t)p0.x * D + sl * 8);
        uint4 g1 = *reinterpret_cast<const uint4*>(hb + (size_t)p0.z * D + sl * 8);
        uint4 g2 = *reinterpret_cast<const uint4*>(hb + (size_t)p1.x * D + sl * 8);
        uint4 g3 = *reinterpret_cast<const uint4*>(hb + (size_t)p1.z * D + sl * 8);
        fma8(__int_as_float(p0.y), g0, acc);
        fma8(__int_as_float(p0.w), g1, acc);
        fma8(__int_as_float(p1.y), g2, acc);
        fma8(__int_as_float(p1.w), g3, acc);
    }
    if (j + 2 <= end) {
        int4 p0 = *reinterpret_cast<const int4*>(&csr[j]);
        uint4 g0 = *reinterpret_cast<const uint4*>(hb + (size_t)p0.x * D + sl * 8);
        uint4 g1 = *reinterpret_cast<const uint4*>(hb + (size_t)p0.z * D + sl * 8);
        fma8(__int_as_float(p0.y), g0, acc);
        fma8(__int_as_float(p0.w), g1, acc);
        j += 2;
    }
    if (j < end) {
        int2 e0 = csr[j];
        uint4 g0 = *reinterpret_cast<const uint4*>(hb + (size_t)e0.x * D + sl * 8);
        fma8(__int_as_float(e0.y), g0, acc);
    }
    if (BIAS_RELU) {
        float4 b0 = *reinterpret_cast<const float4*>(bias + sl * 8);
        float4 b1 = *reinterpret_cast<const float4*>(bias + sl * 8 + 4);
        acc[0] = fmaxf(acc[0] + b0.x, 0.f); acc[1] = fmaxf(acc[1] + b0.y, 0.f);
        acc[2] = fmaxf(acc[2] + b0.z, 0.f); acc[3] = fmaxf(acc[3] + b0.w, 0.f);
        acc[4] = fmaxf(acc[4] + b1.x, 0.f); acc[5] = fmaxf(acc[5] + b1.y, 0.f);
        acc[6] = fmaxf(acc[6] + b1.z, 0.f); acc[7] = fmaxf(acc[7] + b1.w, 0.f);
    }
    if (BF16OUT) {
        uint4 o;
        o.x = f2b(acc[0]) | (f2b(acc[1]) << 16);
        o.y = f2b(acc[2]) | (f2b(acc[3]) << 16);
        o.z = f2b(acc[4]) | (f2b(acc[5]) << 16);
        o.w = f2b(acc[6]) | (f2b(acc[7]) << 16);
        *reinterpret_cast<uint4*>(reinterpret_cast<ushort*>(out) + (size_t)node * D + sl * 8) = o;
    } else {
        float* op = reinterpret_cast<float*>(out) + (size_t)node * D + sl * 8;
        *reinterpret_cast<float4*>(op) = make_float4(acc[0], acc[1], acc[2], acc[3]);
        *reinterpret_cast<float4*>(op + 4) = make_float4(acc[4], acc[5], acc[6], acc[7]);
    }
}

// ---------------- GEMM: C_bf16[NN,DH] = A_bf16[NN,DIN] @ W_f32[DIN,DH] (+bias, relu) ----------------
__device__ inline float4 fmaf4(float s, float4 w, float4 a) {
    a.x = fmaf(s, w.x, a.x); a.y = fmaf(s, w.y, a.y);
    a.z = fmaf(s, w.z, a.z); a.w = fmaf(s, w.w, a.w);
    return a;
}

template <int DIN, bool BIAS_RELU>
__global__ __launch_bounds__(256) void k_gemm3b(const ushort* __restrict__ A,
                                                const float* __restrict__ W,
                                                const float* __restrict__ bias,
                                                u32* __restrict__ C) {
    constexpr int KT = 32;
    constexpr int NT = DIN / KT;
    constexpr int AP = KT + 4;
    __shared__ float sW[KT * DH];   // [k][c] row-major, 16 KB
    __shared__ float sA[64 * AP];   // [r][k] padded
    const int t = threadIdx.x;
    const int cg = t & 31;
    const int rg = t >> 5;
    const int row0 = blockIdx.x * 64;
    const int sr = t >> 2;
    const int kq = t & 3;

    float4 acc[8];
#pragma unroll
    for (int j = 0; j < 8; ++j) acc[j] = make_float4(0.f, 0.f, 0.f, 0.f);

    for (int tile = 0; tile < NT; ++tile) {
        if (tile) __syncthreads();
        {
            const float4* Wg = reinterpret_cast<const float4*>(W + tile * KT * DH);
            float4* sW4 = reinterpret_cast<float4*>(sW);
#pragma unroll
            for (int i = 0; i < (KT * DH / 4) / 256; ++i)
                sW4[t + 256 * i] = Wg[t + 256 * i];
        }
        {
            int gr = row0 + sr;
            uint4 v = make_uint4(0u, 0u, 0u, 0u);
            if (gr < NN)
                v = *reinterpret_cast<const uint4*>(A + (size_t)gr * DIN + tile * KT + kq * 8);
            *reinterpret_cast<float4*>(&sA[sr * AP + kq * 8]) =
                make_float4(blo(v.x), bhi(v.x), blo(v.y), bhi(v.y));
            *reinterpret_cast<float4*>(&sA[sr * AP + kq * 8 + 4]) =
                make_float4(blo(v.z), bhi(v.z), blo(v.w), bhi(v.w));
        }
        __syncthreads();
#pragma unroll 2
        for (int kk = 0; kk < KT; kk += 4) {
            float4 w0 = *reinterpret_cast<const float4*>(&sW[(kk + 0) * DH + cg * 4]);
            float4 w1 = *reinterpret_cast<const float4*>(&sW[(kk + 1) * DH + cg * 4]);
            float4 w2 = *reinterpret_cast<const float4*>(&sW[(kk + 2) * DH + cg * 4]);
            float4 w3 = *reinterpret_cast<const float4*>(&sW[(kk + 3) * DH + cg * 4]);
#pragma unroll
            for (int j = 0; j < 8; ++j) {
                float4 a = *reinterpret_cast<const float4*>(&sA[(rg * 8 + j) * AP + kk]);
                acc[j] = fmaf4(a.x, w0, acc[j]);
                acc[j] = fmaf4(a.y, w1, acc[j]);
                acc[j] = fmaf4(a.z, w2, acc[j]);
                acc[j] = fmaf4(a.w, w3, acc[j]);
            }
        }
    }
    float4 bb = make_float4(0.f, 0.f, 0.f, 0.f);
    if (BIAS_RELU) bb = *reinterpret_cast<const float4*>(bias + cg * 4);
#pragma unroll
    for (int j = 0; j < 8; ++j) {
        int gr = row0 + rg * 8 + j;
        if (gr < NN) {
            float4 r = acc[j];
            if (BIAS_RELU) {
                r.x = fmaxf(r.x + bb.x, 0.f); r.y = fmaxf(r.y + bb.y, 0.f);
                r.z = fmaxf(r.z + bb.z, 0.f); r.w = fmaxf(r.w + bb.w, 0.f);
            }
            uint2 o = make_uint2(f2b(r.x) | (f2b(r.y) << 16),
                                 f2b(r.z) | (f2b(r.w) << 16));
            *reinterpret_cast<uint2*>(&C[(size_t)gr * (DH / 2) + cg * 2]) = o;
        }
    }
}

// ---------------- pooling ----------------
__global__ void k_gstart_zero(const int* __restrict__ batch, int* __restrict__ gstart,
                              float* __restrict__ pooled) {
    int i = blockIdx.x * blockDim.x + threadIdx.x;
    if (i < NG * DH) pooled[i] = 0.0f;
    if (blockIdx.x == 0 && threadIdx.x <= NG) {
        int g = threadIdx.x;
        int lo = 0, hi = NN;
        while (lo < hi) {
            int mid = (lo + hi) >> 1;
            if (batch[mid] < g) lo = mid + 1; else hi = mid;
        }
        gstart[g] = lo;
    }
}

constexpr int POOL_CHUNK = 64;
__global__ __launch_bounds__(256) void k_pool2(const float* __restrict__ h,
                                               const int* __restrict__ batch,
                                               float* __restrict__ pooled) {
    const int c = threadIdx.x & 127;
    const int half = threadIdx.x >> 7;
    const int n0 = blockIdx.x * POOL_CHUNK;
    const int nEnd = min(n0 + POOL_CHUNK, NN);
    float acc = 0.0f;
    int gcur = -1;
    for (int n = n0 + half; n < nEnd; n += 2) {
        int g = batch[n];
        if (g != gcur) {
            if (gcur >= 0) atomicAdd(&pooled[gcur * DH + c], acc);
            acc = 0.0f;
            gcur = g;
        }
        acc += h[(size_t)n * DH + c];
    }
    if (gcur >= 0) atomicAdd(&pooled[gcur * DH + c], acc);
}

__global__ void k_head(const float* __restrict__ pooled, const int* __restrict__ gstart,
                       const float* __restrict__ Wf, const float* __restrict__ bf,
                       float* __restrict__ out) {
    int t = threadIdx.x;
    if (t >= NG * DO) return;
    int g = t / DO, o = t - g * DO;
    float acc = 0.0f;
    for (int k = 0; k < DH; ++k) acc += pooled[g * DH + k] * Wf[k * DO + o];
    float cnt = fmaxf((float)(gstart[g + 1] - gstart[g]), 1.0f);
    out[t] = acc / cnt + bf[o];
}

extern "C" void kernel_launch(void* const* d_in, const int* in_sizes, int n_in,
                              void* d_out, int out_size, void* d_ws, size_t ws_size,
                              hipStream_t stream) {
    const float* x   = (const float*)d_in[0];
    const int* ei    = (const int*)d_in[1];  // [2, NE] row-major
    const int* batch = (const int*)d_in[2];
    const float* W1  = (const float*)d_in[3];
    const float* b1  = (const float*)d_in[4];
    const float* W2  = (const float*)d_in[5];
    const float* b2  = (const float*)d_in[6];
    const float* Wf  = (const float*)d_in[7];
    const float* bf  = (const float*)d_in[8];
    float* out = (float*)d_out;

    const int* src = ei;
    const int* dst = ei + NE;

    // workspace (4B units; total ~58.2 MB — same proven budget)
    int* cnt      = (int*)d_ws;              // 50048 (reused as cursor after scan3)
    int* rowptr   = cnt + 50048;             // 50056 (NN+1 used)
    int* partial  = rowptr + 50056;          // 256
    int* gstart   = partial + 256;           // 80
    int2* csr     = (int2*)(gstart + 80);    // NE int2 (byte off 401760, 16B-aligned)
    float* dinv   = (float*)(csr + NE);      // 50048
    u32* R1       = (u32*)(dinv + 50048);    // 3.2M units: xb (first 1.6M) then h1b
    u32* R2       = R1 + 3200000;            // 3.2M units: agg1b (first 1.6M) then tb
    float* h2     = (float*)(R2 + 3200000);  // 6.4M units
    float* pooled = h2 + 6400000;            // 8192

    ushort* xb    = (ushort*)R1;   // NN x 64 bf16 (dead after agg1)
    ushort* h1b   = (ushort*)R1;   // NN x 128 bf16 (written by gemm1, after agg1)
    ushort* agg1b = (ushort*)R2;   // NN x 64 bf16 (dead after gemm1)
    ushort* tb    = (ushort*)R2;   // NN x 128 bf16 (written by gemm2)

    const int B = 256;
    k_tobf16<<<(NN * DI / 8 + B - 1) / B, B, 0, stream>>>(x, (uint4*)xb);
    k_zero_cnt<<<(NN + B - 1) / B, B, 0, stream>>>(cnt);
    k_hist<<<(NE + B - 1) / B, B, 0, stream>>>(dst, cnt);
    k_scan1<<<NB_SCAN, SCAN_B, 0, stream>>>(cnt, rowptr, partial);
    k_scan2<<<1, SCAN_B, 0, stream>>>(partial);
    k_scan3<<<(NN + B) / B, B, 0, stream>>>(rowptr, partial, cnt /*cursor*/, dinv);
    k_fill<<<(NE + B - 1) / B, B, 0, stream>>>(src, dst, cnt /*cursor*/, dinv, csr);

    const int gemmGrid = (NN + 63) / 64;  // 782

    // layer 1: agg in 64-d (bf16 table), then GEMM (+bias+relu) -> h1 bf16
    k_aggb<DI, false, true><<<(NN + 31) / 32, 256, 0, stream>>>(xb, csr, rowptr, dinv,
                                                                nullptr, agg1b);
    k_gemm3b<DI, true><<<gemmGrid, 256, 0, stream>>>(agg1b, W1, b1, (u32*)h1b);

    // layer 2: GEMM -> t bf16, then agg (+bias+relu) -> h2 f32
    k_gemm3b<DH, false><<<gemmGrid, 256, 0, stream>>>(h1b, W2, nullptr, (u32*)tb);
    k_aggb<DH, true, false><<<(NN + 15) / 16, 256, 0, stream>>>(tb, csr, rowptr, dinv,
                                                                b2, h2);

    // pool + head
    k_gstart_zero<<<32, 256, 0, stream>>>(batch, gstart, pooled);
    k_pool2<<<(NN + POOL_CHUNK - 1) / POOL_CHUNK, 256, 0, stream>>>(h2, batch, pooled);
    k_head<<<1, 256, 0, stream>>>(pooled, gstart, Wf, bf, out);
}

// Round 11
// 228.258 us; speedup vs baseline: 1.5407x; 1.0165x over previous
//
#include <hip/hip_runtime.h>
#include <hip/hip_fp16.h>

constexpr int NN = 50000;   // nodes
constexpr int NE = 800000;  // edges
constexpr int NG = 64;      // graphs
constexpr int DI = 64;      // in dim
constexpr int DH = 128;     // hidden dim
constexpr int DO = 3;       // out dim

constexpr int SCAN_B = 256;
constexpr int NB_SCAN = (NN + SCAN_B - 1) / SCAN_B;  // 196

typedef unsigned int u32;

// ---------------- bf16 / fp16 helpers ----------------
__device__ inline float blo(u32 u) { return __uint_as_float(u << 16); }
__device__ inline float bhi(u32 u) { return __uint_as_float(u & 0xffff0000u); }
__device__ inline u32 f2b(float f) {  // RNE round to bf16 (16-bit pattern)
    u32 u = __float_as_uint(f);
    return (u + 0x7fffu + ((u >> 16) & 1u)) >> 16;
}
__device__ inline float wof(u32 e) {  // fp16 weight from high 16 bits
    __half h;
    reinterpret_cast<ushort&>(h) = (ushort)(e >> 16);
    return __half2float(h);
}
__device__ inline void fma8(float w, uint4 v, float acc[8]) {
    acc[0] = fmaf(w, blo(v.x), acc[0]); acc[1] = fmaf(w, bhi(v.x), acc[1]);
    acc[2] = fmaf(w, blo(v.y), acc[2]); acc[3] = fmaf(w, bhi(v.y), acc[3]);
    acc[4] = fmaf(w, blo(v.z), acc[4]); acc[5] = fmaf(w, bhi(v.z), acc[5]);
    acc[6] = fmaf(w, blo(v.w), acc[6]); acc[7] = fmaf(w, bhi(v.w), acc[7]);
}

// ---------------- fused: x -> bf16 AND zero cnt ----------------
__global__ void k_init(const float* __restrict__ x, uint4* __restrict__ xb,
                       int* __restrict__ cnt) {
    int i = blockIdx.x * blockDim.x + threadIdx.x;
    if (i < NN * DI / 8) {
        float4 a = reinterpret_cast<const float4*>(x)[i * 2];
        float4 b = reinterpret_cast<const float4*>(x)[i * 2 + 1];
        uint4 o;
        o.x = f2b(a.x) | (f2b(a.y) << 16);
        o.y = f2b(a.z) | (f2b(a.w) << 16);
        o.z = f2b(b.x) | (f2b(b.y) << 16);
        o.w = f2b(b.z) | (f2b(b.w) << 16);
        xb[i] = o;
    }
    if (i < NN) cnt[i] = 0;
}

// ---------------- CSR build ----------------
__global__ void k_hist(const int* __restrict__ dst, int* __restrict__ cnt) {
    int e = blockIdx.x * blockDim.x + threadIdx.x;
    if (e < NE) atomicAdd(&cnt[dst[e]], 1);
}

__global__ void k_scan1(const int* __restrict__ cnt, int* __restrict__ rowptr,
                        int* __restrict__ partial) {
    __shared__ int sm[SCAN_B];
    int i = blockIdx.x * SCAN_B + threadIdx.x;
    int v = (i < NN) ? cnt[i] : 0;
    sm[threadIdx.x] = v;
    __syncthreads();
    for (int off = 1; off < SCAN_B; off <<= 1) {
        int add = (threadIdx.x >= off) ? sm[threadIdx.x - off] : 0;
        __syncthreads();
        sm[threadIdx.x] += add;
        __syncthreads();
    }
    if (i < NN) rowptr[i] = sm[threadIdx.x] - v;  // block-local exclusive
    if (threadIdx.x == SCAN_B - 1) partial[blockIdx.x] = sm[SCAN_B - 1];
}

__global__ void k_scan2(int* partial) {  // single block, NB_SCAN <= 256
    __shared__ int sm[SCAN_B];
    int v = (threadIdx.x < NB_SCAN) ? partial[threadIdx.x] : 0;
    sm[threadIdx.x] = v;
    __syncthreads();
    for (int off = 1; off < SCAN_B; off <<= 1) {
        int add = (threadIdx.x >= off) ? sm[threadIdx.x - off] : 0;
        __syncthreads();
        sm[threadIdx.x] += add;
        __syncthreads();
    }
    if (threadIdx.x < NB_SCAN) partial[threadIdx.x] = sm[threadIdx.x] - v;  // exclusive
}

// finalizes rowptr, computes dinv from cnt, then re-inits cnt as the fill cursor
__global__ void k_scan3(int* __restrict__ rowptr, const int* __restrict__ partial,
                        int* __restrict__ cnt_cursor, float* __restrict__ dinv) {
    int i = blockIdx.x * blockDim.x + threadIdx.x;
    if (i < NN) {
        int r = rowptr[i] + partial[i >> 8];
        rowptr[i] = r;
        dinv[i] = rsqrtf((float)(cnt_cursor[i] + 1));  // read cnt BEFORE overwrite
        cnt_cursor[i] = r;
    }
    if (i == NN) rowptr[NN] = NE;
}

// fill packed entry per edge: u32 = (fp16(w) << 16) | src  (src < 65536 OK)
__global__ void k_fill(const int* __restrict__ src, const int* __restrict__ dst,
                       int* __restrict__ cursor, const float* __restrict__ dinv,
                       u32* __restrict__ csr) {
    int e = blockIdx.x * blockDim.x + threadIdx.x;
    if (e < NE) {
        int s = src[e], d = dst[e];
        int slot = atomicAdd(&cursor[d], 1);
        float w = dinv[s] * dinv[d];
        __half hw = __float2half(w);
        csr[slot] = ((u32)reinterpret_cast<ushort&>(hw) << 16) | (u32)s;
    }
}

// ---------------- gather aggregation over a bf16 table, packed 4B edges ----------------
// out[n] = dinv[n]^2*hb[n] + sum_in w_e * hb[src_e]   (+bias, relu)
template <int D, bool BIAS_RELU, bool BF16OUT>
__global__ __launch_bounds__(256) void k_aggc(const ushort* __restrict__ hb,
                                              const u32* __restrict__ csr,
                                              const int* __restrict__ rowptr,
                                              const float* __restrict__ dinv,
                                              const float* __restrict__ bias,
                                              void* __restrict__ out) {
    constexpr int SUB = D / 8;        // lanes per node (8 for D=64, 16 for D=128)
    constexpr int NPB = 256 / SUB;    // nodes per block
    const int sub = threadIdx.x / SUB;
    const int sl = threadIdx.x % SUB;
    const int node = blockIdx.x * NPB + sub;
    if (node >= NN) return;

    const float dn = dinv[node];
    float acc[8];
    {
        uint4 v = *reinterpret_cast<const uint4*>(hb + (size_t)node * D + sl * 8);
        float w = dn * dn;
        acc[0] = w * blo(v.x); acc[1] = w * bhi(v.x);
        acc[2] = w * blo(v.y); acc[3] = w * bhi(v.y);
        acc[4] = w * blo(v.z); acc[5] = w * bhi(v.z);
        acc[6] = w * blo(v.w); acc[7] = w * bhi(v.w);
    }
    int j = rowptr[node];
    const int end = rowptr[node + 1];
    // peel to 16B boundary for uint4 edge loads
    while ((j & 3) && j < end) {
        u32 e = csr[j];
        uint4 g = *reinterpret_cast<const uint4*>(hb + (size_t)(e & 0xffffu) * D + sl * 8);
        fma8(wof(e), g, acc);
        ++j;
    }
    // main: 4 edges per iteration (one uint4 index load, 4 independent gathers)
    for (; j + 4 <= end; j += 4) {
        uint4 p = *reinterpret_cast<const uint4*>(&csr[j]);
        uint4 g0 = *reinterpret_cast<const uint4*>(hb + (size_t)(p.x & 0xffffu) * D + sl * 8);
        uint4 g1 = *reinterpret_cast<const uint4*>(hb + (size_t)(p.y & 0xffffu) * D + sl * 8);
        uint4 g2 = *reinterpret_cast<const uint4*>(hb + (size_t)(p.z & 0xffffu) * D + sl * 8);
        uint4 g3 = *reinterpret_cast<const uint4*>(hb + (size_t)(p.w & 0xffffu) * D + sl * 8);
        fma8(wof(p.x), g0, acc);
        fma8(wof(p.y), g1, acc);
        fma8(wof(p.z), g2, acc);
        fma8(wof(p.w), g3, acc);
    }
    while (j < end) {
        u32 e = csr[j];
        uint4 g = *reinterpret_cast<const uint4*>(hb + (size_t)(e & 0xffffu) * D + sl * 8);
        fma8(wof(e), g, acc);
        ++j;
    }
    if (BIAS_RELU) {
        float4 b0 = *reinterpret_cast<const float4*>(bias + sl * 8);
        float4 b1 = *reinterpret_cast<const float4*>(bias + sl * 8 + 4);
        acc[0] = fmaxf(acc[0] + b0.x, 0.f); acc[1] = fmaxf(acc[1] + b0.y, 0.f);
        acc[2] = fmaxf(acc[2] + b0.z, 0.f); acc[3] = fmaxf(acc[3] + b0.w, 0.f);
        acc[4] = fmaxf(acc[4] + b1.x, 0.f); acc[5] = fmaxf(acc[5] + b1.y, 0.f);
        acc[6] = fmaxf(acc[6] + b1.z, 0.f); acc[7] = fmaxf(acc[7] + b1.w, 0.f);
    }
    if (BF16OUT) {
        uint4 o;
        o.x = f2b(acc[0]) | (f2b(acc[1]) << 16);
        o.y = f2b(acc[2]) | (f2b(acc[3]) << 16);
        o.z = f2b(acc[4]) | (f2b(acc[5]) << 16);
        o.w = f2b(acc[6]) | (f2b(acc[7]) << 16);
        *reinterpret_cast<uint4*>(reinterpret_cast<ushort*>(out) + (size_t)node * D + sl * 8) = o;
    } else {
        float* op = reinterpret_cast<float*>(out) + (size_t)node * D + sl * 8;
        *reinterpret_cast<float4*>(op) = make_float4(acc[0], acc[1], acc[2], acc[3]);
        *reinterpret_cast<float4*>(op + 4) = make_float4(acc[4], acc[5], acc[6], acc[7]);
    }
}

// ---------------- GEMM: C_bf16[NN,DH] = A_bf16[NN,DIN] @ W_f32[DIN,DH] (+bias, relu) ----------------
__device__ inline float4 fmaf4(float s, float4 w, float4 a) {
    a.x = fmaf(s, w.x, a.x); a.y = fmaf(s, w.y, a.y);
    a.z = fmaf(s, w.z, a.z); a.w = fmaf(s, w.w, a.w);
    return a;
}

template <int DIN, bool BIAS_RELU>
__global__ __launch_bounds__(256) void k_gemm3b(const ushort* __restrict__ A,
                                                const float* __restrict__ W,
                                                const float* __restrict__ bias,
                                                u32* __restrict__ C) {
    constexpr int KT = 32;
    constexpr int NT = DIN / KT;
    constexpr int AP = KT + 4;
    __shared__ float sW[KT * DH];   // [k][c] row-major, 16 KB
    __shared__ float sA[64 * AP];   // [r][k] padded
    const int t = threadIdx.x;
    const int cg = t & 31;
    const int rg = t >> 5;
    const int row0 = blockIdx.x * 64;
    const int sr = t >> 2;
    const int kq = t & 3;

    float4 acc[8];
#pragma unroll
    for (int j = 0; j < 8; ++j) acc[j] = make_float4(0.f, 0.f, 0.f, 0.f);

    for (int tile = 0; tile < NT; ++tile) {
        if (tile) __syncthreads();
        {
            const float4* Wg = reinterpret_cast<const float4*>(W + tile * KT * DH);
            float4* sW4 = reinterpret_cast<float4*>(sW);
#pragma unroll
            for (int i = 0; i < (KT * DH / 4) / 256; ++i)
                sW4[t + 256 * i] = Wg[t + 256 * i];
        }
        {
            int gr = row0 + sr;
            uint4 v = make_uint4(0u, 0u, 0u, 0u);
            if (gr < NN)
                v = *reinterpret_cast<const uint4*>(A + (size_t)gr * DIN + tile * KT + kq * 8);
            *reinterpret_cast<float4*>(&sA[sr * AP + kq * 8]) =
                make_float4(blo(v.x), bhi(v.x), blo(v.y), bhi(v.y));
            *reinterpret_cast<float4*>(&sA[sr * AP + kq * 8 + 4]) =
                make_float4(blo(v.z), bhi(v.z), blo(v.w), bhi(v.w));
        }
        __syncthreads();
#pragma unroll 2
        for (int kk = 0; kk < KT; kk += 4) {
            float4 w0 = *reinterpret_cast<const float4*>(&sW[(kk + 0) * DH + cg * 4]);
            float4 w1 = *reinterpret_cast<const float4*>(&sW[(kk + 1) * DH + cg * 4]);
            float4 w2 = *reinterpret_cast<const float4*>(&sW[(kk + 2) * DH + cg * 4]);
            float4 w3 = *reinterpret_cast<const float4*>(&sW[(kk + 3) * DH + cg * 4]);
#pragma unroll
            for (int j = 0; j < 8; ++j) {
                float4 a = *reinterpret_cast<const float4*>(&sA[(rg * 8 + j) * AP + kk]);
                acc[j] = fmaf4(a.x, w0, acc[j]);
                acc[j] = fmaf4(a.y, w1, acc[j]);
                acc[j] = fmaf4(a.z, w2, acc[j]);
                acc[j] = fmaf4(a.w, w3, acc[j]);
            }
        }
    }
    float4 bb = make_float4(0.f, 0.f, 0.f, 0.f);
    if (BIAS_RELU) bb = *reinterpret_cast<const float4*>(bias + cg * 4);
#pragma unroll
    for (int j = 0; j < 8; ++j) {
        int gr = row0 + rg * 8 + j;
        if (gr < NN) {
            float4 r = acc[j];
            if (BIAS_RELU) {
                r.x = fmaxf(r.x + bb.x, 0.f); r.y = fmaxf(r.y + bb.y, 0.f);
                r.z = fmaxf(r.z + bb.z, 0.f); r.w = fmaxf(r.w + bb.w, 0.f);
            }
            uint2 o = make_uint2(f2b(r.x) | (f2b(r.y) << 16),
                                 f2b(r.z) | (f2b(r.w) << 16));
            *reinterpret_cast<uint2*>(&C[(size_t)gr * (DH / 2) + cg * 2]) = o;
        }
    }
}

// ---------------- pooling (bf16 input, coalesced u32 reads) ----------------
__global__ void k_gstart_zero(const int* __restrict__ batch, int* __restrict__ gstart,
                              float* __restrict__ pooled) {
    int i = blockIdx.x * blockDim.x + threadIdx.x;
    if (i < NG * DH) pooled[i] = 0.0f;
    if (blockIdx.x == 0 && threadIdx.x <= NG) {
        int g = threadIdx.x;
        int lo = 0, hi = NN;
        while (lo < hi) {
            int mid = (lo + hi) >> 1;
            if (batch[mid] < g) lo = mid + 1; else hi = mid;
        }
        gstart[g] = lo;
    }
}

constexpr int POOL_CHUNK = 64;
__global__ __launch_bounds__(256) void k_pool3(const u32* __restrict__ h2b,
                                               const int* __restrict__ batch,
                                               float* __restrict__ pooled) {
    const int c2 = threadIdx.x & 63;   // channel pair (2 bf16 per u32)
    const int q = threadIdx.x >> 6;    // 0..3: 4-way node interleave
    const int n0 = blockIdx.x * POOL_CHUNK;
    const int nEnd = min(n0 + POOL_CHUNK, NN);
    float a0 = 0.f, a1 = 0.f;
    int gcur = -1;
    for (int n = n0 + q; n < nEnd; n += 4) {
        int g = batch[n];
        if (g != gcur) {
            if (gcur >= 0) {
                atomicAdd(&pooled[gcur * DH + c2 * 2], a0);
                atomicAdd(&pooled[gcur * DH + c2 * 2 + 1], a1);
            }
            a0 = a1 = 0.f;
            gcur = g;
        }
        u32 v = h2b[(size_t)n * (DH / 2) + c2];
        a0 += blo(v);
        a1 += bhi(v);
    }
    if (gcur >= 0) {
        atomicAdd(&pooled[gcur * DH + c2 * 2], a0);
        atomicAdd(&pooled[gcur * DH + c2 * 2 + 1], a1);
    }
}

__global__ void k_head(const float* __restrict__ pooled, const int* __restrict__ gstart,
                       const float* __restrict__ Wf, const float* __restrict__ bf,
                       float* __restrict__ out) {
    int t = threadIdx.x;
    if (t >= NG * DO) return;
    int g = t / DO, o = t - g * DO;
    float acc = 0.0f;
    for (int k = 0; k < DH; ++k) acc += pooled[g * DH + k] * Wf[k * DO + o];
    float cnt = fmaxf((float)(gstart[g + 1] - gstart[g]), 1.0f);
    out[t] = acc / cnt + bf[o];
}

extern "C" void kernel_launch(void* const* d_in, const int* in_sizes, int n_in,
                              void* d_out, int out_size, void* d_ws, size_t ws_size,
                              hipStream_t stream) {
    const float* x   = (const float*)d_in[0];
    const int* ei    = (const int*)d_in[1];  // [2, NE] row-major
    const int* batch = (const int*)d_in[2];
    const float* W1  = (const float*)d_in[3];
    const float* b1  = (const float*)d_in[4];
    const float* W2  = (const float*)d_in[5];
    const float* b2  = (const float*)d_in[6];
    const float* Wf  = (const float*)d_in[7];
    const float* bf  = (const float*)d_in[8];
    float* out = (float*)d_out;

    const int* src = ei;
    const int* dst = ei + NE;

    // workspace (4B units; ~42.3 MB total)
    int* cnt      = (int*)d_ws;              // 50048 (reused as cursor after scan3)
    int* rowptr   = cnt + 50048;             // 50056 (NN+1 used)
    int* partial  = rowptr + 50056;          // 256
    int* gstart   = partial + 256;           // 80
    u32* csr      = (u32*)(gstart + 80);     // NE u32 (byte off 401760, 16B-aligned)
    float* dinv   = (float*)(csr + NE);      // 50048
    u32* R1       = (u32*)(dinv + 50048);    // 3.2M units: xb (first 1.6M) then h1b
    u32* R2       = R1 + 3200000;            // 3.2M units: agg1b (first 1.6M) then tb
    u32* h2b      = R2 + 3200000;            // 3.2M units (NN x 128 bf16)  [round-10 bug: was 1.6M]
    float* pooled = (float*)(h2b + 3200000); // 8192

    ushort* xb    = (ushort*)R1;   // NN x 64 bf16 (dead after agg1)
    ushort* h1b   = (ushort*)R1;   // NN x 128 bf16 (written by gemm1, after agg1)
    ushort* agg1b = (ushort*)R2;   // NN x 64 bf16 (dead after gemm1)
    ushort* tb    = (ushort*)R2;   // NN x 128 bf16 (written by gemm2)

    const int B = 256;
    k_init<<<(NN * DI / 8 + B - 1) / B, B, 0, stream>>>(x, (uint4*)xb, cnt);
    k_hist<<<(NE + B - 1) / B, B, 0, stream>>>(dst, cnt);
    k_scan1<<<NB_SCAN, SCAN_B, 0, stream>>>(cnt, rowptr, partial);
    k_scan2<<<1, SCAN_B, 0, stream>>>(partial);
    k_scan3<<<(NN + B) / B, B, 0, stream>>>(rowptr, partial, cnt /*cursor*/, dinv);
    k_fill<<<(NE + B - 1) / B, B, 0, stream>>>(src, dst, cnt /*cursor*/, dinv, csr);

    const int gemmGrid = (NN + 63) / 64;  // 782

    // layer 1: agg in 64-d (bf16 table), then GEMM (+bias+relu) -> h1 bf16
    k_aggc<DI, false, true><<<(NN + 31) / 32, 256, 0, stream>>>(xb, csr, rowptr, dinv,
                                                                nullptr, agg1b);
    k_gemm3b<DI, true><<<gemmGrid, 256, 0, stream>>>(agg1b, W1, b1, (u32*)h1b);

    // layer 2: GEMM -> t bf16, then agg (+bias+relu) -> h2 bf16
    k_gemm3b<DH, false><<<gemmGrid, 256, 0, stream>>>(h1b, W2, nullptr, (u32*)tb);
    k_aggc<DH, true, true><<<(NN + 15) / 16, 256, 0, stream>>>(tb, csr, rowptr, dinv,
                                                               b2, (void*)h2b);

    // pool + head
    k_gstart_zero<<<32, 256, 0, stream>>>(batch, gstart, pooled);
    k_pool3<<<(NN + POOL_CHUNK - 1) / POOL_CHUNK, 256, 0, stream>>>(h2b, batch, pooled);
    k_head<<<1, 256, 0, stream>>>(pooled, gstart, Wf, bf, out);
}